// Round 5
// baseline (236.470 us; speedup 1.0000x reference)
//
#include <hip/hip_runtime.h>
#include <math.h>

#define BATCH 32
#define NTOK 577
#define NPATCH 576
#define CDIM 768
#define HEADS 12
#define DHEAD 64
#define W3 2304
#define FT 404

// ---- workspace layout (float offsets) ----
#define WS_WTIL  24576      // 32*12*768         -> 319488
#define WS_DBIAS 319488     // 32*12             -> 319872
#define WS_DOTS  319872     // 32*12*577         -> 541440
#define WS_IND   541440     // 32*404 (as int)   -> 554368

// ---- output layout (float offsets) ----
#define O_X      0ULL
#define O_INDEX  14180352ULL
#define O_IND    24109056ULL
#define O_CA     24121984ULL
#define O_FT     24140416ULL

#define NIDX4  2482176   // 32*404*768/4  float4 of index broadcast
#define NCOPY4 3545088   // 32*577*768/4  float4 of x->out copy

// K_fold: unchanged (round-3 design; ~20-27 us by subtraction).
__global__ __launch_bounds__(512) void k_fold(const float* __restrict__ x,
                                              const float* __restrict__ W,
                                              const float* __restrict__ bq,
                                              float* __restrict__ wtil,
                                              float* __restrict__ dbias) {
    __shared__ float x0s[CDIM];
    __shared__ float red[512];
    __shared__ float qs[DHEAD];
    const int b = blockIdx.x, h = blockIdx.y, tid = threadIdx.x;
    if (tid < CDIM / 4)
        ((float4*)x0s)[tid] = ((const float4*)(x + (size_t)b * NTOK * CDIM))[tid];
    __syncthreads();
    {
        const int d = tid & 63, seg = tid >> 6;
        const float* Wq = W + h * DHEAD + d;
        const int c0 = seg * 96;
        float acc = 0.f;
        #pragma unroll 32
        for (int c = c0; c < c0 + 96; c++) acc += x0s[c] * Wq[(size_t)c * W3];
        red[tid] = acc;
    }
    __syncthreads();
    if (tid < DHEAD) {
        float q = red[tid];
        #pragma unroll
        for (int s = 1; s < 8; s++) q += red[tid + s * 64];
        q += bq[h * DHEAD + tid];
        qs[tid] = q;
        float t = q * bq[CDIM + h * DHEAD + tid];
        #pragma unroll
        for (int off = 32; off; off >>= 1) t += __shfl_down(t, off);
        if (tid == 0) dbias[b * HEADS + h] = t;
    }
    __syncthreads();
    for (int c = tid; c < CDIM; c += 512) {
        const float* wr = W + (size_t)c * W3 + CDIM + h * DHEAD;
        float acc = 0.f;
        #pragma unroll
        for (int d = 0; d < DHEAD; d += 4) {
            float4 a = *reinterpret_cast<const float4*>(wr + d);
            acc += a.x * qs[d] + a.y * qs[d + 1] + a.z * qs[d + 2] + a.w * qs[d + 3];
        }
        wtil[((size_t)b * HEADS + h) * CDIM + c] = acc;
    }
}

// K_dots v4: read-only (copy moved to k_bcast). Same 2-deep pipelined 4-row
// groups; accumulation order and shfl butterfly bit-identical to verified.
#define LOADG(A, G)                                                               \
    {                                                                             \
        _Pragma("unroll")                                                         \
        for (int u = 0; u < 4; u++) {                                             \
            const int j = jbase + (G) * 4 + u;                                    \
            if (j < NTOK) {                                                       \
                const float4* xp =                                                \
                    (const float4*)(x + ((size_t)b * NTOK + j) * CDIM);           \
                A[u][0] = xp[lane]; A[u][1] = xp[64 + lane]; A[u][2] = xp[128 + lane]; \
            } else {                                                              \
                A[u][0] = A[u][1] = A[u][2] = make_float4(0.f, 0.f, 0.f, 0.f);    \
            }                                                                     \
        }                                                                         \
    }

#define COMPG(A, G)                                                               \
    {                                                                             \
        float acc[4][3];                                                          \
        _Pragma("unroll")                                                         \
        for (int u = 0; u < 4; u++) { acc[u][0] = acc[u][1] = acc[u][2] = 0.f; }  \
        _Pragma("unroll")                                                         \
        for (int i = 0; i < 3; i++)                                               \
            _Pragma("unroll")                                                     \
            for (int u = 0; u < 4; u++)                                           \
                _Pragma("unroll")                                                 \
                for (int hh = 0; hh < 3; hh++)                                    \
                    acc[u][hh] += A[u][i].x * wr[hh][i].x + A[u][i].y * wr[hh][i].y \
                                + A[u][i].z * wr[hh][i].z + A[u][i].w * wr[hh][i].w; \
        _Pragma("unroll")                                                         \
        for (int off = 32; off; off >>= 1)                                        \
            _Pragma("unroll")                                                     \
            for (int u = 0; u < 4; u++)                                           \
                _Pragma("unroll")                                                 \
                for (int hh = 0; hh < 3; hh++)                                    \
                    acc[u][hh] += __shfl_xor(acc[u][hh], off);                    \
        if (lane == 0) {                                                          \
            _Pragma("unroll")                                                     \
            for (int u = 0; u < 4; u++) {                                         \
                const int j = jbase + (G) * 4 + u;                                \
                if (j < NTOK) {                                                   \
                    _Pragma("unroll")                                             \
                    for (int hh = 0; hh < 3; hh++)                                \
                        dots[((size_t)b * HEADS + h0 + hh) * NTOK + j] =          \
                            0.125f * (acc[u][hh] + db[hh]);                       \
                }                                                                 \
            }                                                                     \
        }                                                                         \
    }

__global__ __launch_bounds__(256, 3) void k_dots(const float* __restrict__ x,
                                                 const float* __restrict__ wtil,
                                                 const float* __restrict__ dbias,
                                                 float* __restrict__ dots) {
    const int b = blockIdx.x, tid = threadIdx.x;
    const int w = tid >> 6, lane = tid & 63, h0 = w * 3;
    float4 wr[3][3];
    float db[3];
    #pragma unroll
    for (int hh = 0; hh < 3; hh++) {
        #pragma unroll
        for (int i = 0; i < 3; i++)
            wr[hh][i] = *reinterpret_cast<const float4*>(
                wtil + ((size_t)b * HEADS + h0 + hh) * CDIM + i * 256 + lane * 4);
        db[hh] = dbias[b * HEADS + h0 + hh];
    }
    const int jbase = blockIdx.y * 16;
    float4 abuf[4][3], nbuf[4][3];
    LOADG(abuf, 0);
    LOADG(nbuf, 1);
    COMPG(abuf, 0);
    LOADG(abuf, 2);
    COMPG(nbuf, 1);
    LOADG(nbuf, 3);
    COMPG(abuf, 2);
    COMPG(nbuf, 3);
}

// K_catopk: ONE block per batch (512 thr) computes softmax stats, ca, rank,
// compaction; writes ca/ind outputs + compact ind to ws. Rank logic identical
// to verified version (same segment mapping s=w, s+=8).
__global__ __launch_bounds__(512) void k_catopk(const float* __restrict__ dots,
                                                float* __restrict__ out,
                                                int* __restrict__ indws,
                                                int write_ft) {
    __shared__ float dl[HEADS * NTOK];        // 27.7 KB
    __shared__ float mh[HEADS], sh[HEADS];
    __shared__ unsigned vals[NPATCH];
    __shared__ unsigned long long segmask[9];
    __shared__ int segoff[9];
    const int b = blockIdx.x, tid = threadIdx.x;
    {
        const float4* s4 = (const float4*)(dots + (size_t)b * HEADS * NTOK);
        float4* d4 = (float4*)dl;
        for (int i = tid; i < HEADS * NTOK / 4; i += 512) d4[i] = s4[i];   // 1731 float4
    }
    __syncthreads();
    const int w = tid >> 6, lane = tid & 63;
    for (int h = w; h < HEADS; h += 8) {
        const float* row = dl + h * NTOK;
        float m = -3.4e38f;
        for (int j = lane; j < NTOK; j += 64) m = fmaxf(m, row[j]);
        #pragma unroll
        for (int off = 32; off; off >>= 1) m = fmaxf(m, __shfl_xor(m, off));
        float s = 0.f;
        for (int j = lane; j < NTOK; j += 64) s += expf(row[j] - m);
        #pragma unroll
        for (int off = 32; off; off >>= 1) s += __shfl_xor(s, off);
        if (lane == 0) { mh[h] = m; sh[h] = s; }
    }
    __syncthreads();
    for (int t = tid; t < NPATCH; t += 512) {
        float ca = 0.f;
        #pragma unroll
        for (int h = 0; h < HEADS; h++)
            ca += expf(dl[h * NTOK + 1 + t] - mh[h]) / sh[h];
        ca *= (1.f / 12.f);
        out[O_CA + (size_t)b * NPATCH + t] = ca;
        vals[t] = __float_as_uint(ca);   // ca > 0 -> bit order == value order
    }
    __syncthreads();
    {
        const uint4* v4 = (const uint4*)vals;
        for (int s = w; s < 9; s += 8) {
            const int t = s * 64 + lane;
            const unsigned myv = vals[t];
            int rank = 0;
            #pragma unroll 8
            for (int j4 = 0; j4 < NPATCH / 4; j4++) {
                const uint4 vv = v4[j4];
                const int j = j4 * 4;
                rank += (vv.x > myv) || (vv.x == myv && j     < t);
                rank += (vv.y > myv) || (vv.y == myv && j + 1 < t);
                rank += (vv.z > myv) || (vv.z == myv && j + 2 < t);
                rank += (vv.w > myv) || (vv.w == myv && j + 3 < t);
            }
            const unsigned long long mask = __ballot(rank < FT);
            if (lane == 0) segmask[s] = mask;
        }
    }
    __syncthreads();
    if (tid == 0) {
        int acc = 0;
        #pragma unroll
        for (int s = 0; s < 9; s++) { segoff[s] = acc; acc += __popcll(segmask[s]); }
    }
    __syncthreads();
    for (int s = w; s < 9; s += 8) {
        const int t = s * 64 + lane;
        const unsigned long long mask = segmask[s];
        if ((mask >> lane) & 1ull) {
            const int pos = segoff[s] + __popcll(mask & ((1ull << lane) - 1ull));
            indws[b * FT + pos] = t;
            out[O_IND + (size_t)b * FT + pos] = (float)t;
        }
    }
    if (b == 0 && tid == 0 && write_ft) out[O_FT] = (float)FT;
}

// K_bcast: pure streaming writer. Covers (a) index broadcast 39.7 MB from
// compact ind, (b) x->out copy 113.4 MB. Grid-stride, 2048 blocks.
__global__ __launch_bounds__(256) void k_bcast(const int* __restrict__ ind,
                                               const float* __restrict__ x,
                                               float* __restrict__ out) {
    const float4* x4 = (const float4*)x;
    float4* o4 = (float4*)(out + O_X);
    float4* i4 = (float4*)(out + O_INDEX);
    const unsigned stride = gridDim.x * 256u;
    for (unsigned g = blockIdx.x * 256u + threadIdx.x; g < NIDX4 + NCOPY4; g += stride) {
        if (g < NCOPY4) {
            o4[g] = x4[g];
        } else {
            const unsigned e = g - NCOPY4;
            const unsigned row = e / 192u;       // 192 float4 per 768-float row
            const float v = (float)ind[row];
            float4 o; o.x = v; o.y = v; o.z = v; o.w = v;
            i4[e] = o;
        }
    }
}

extern "C" void kernel_launch(void* const* d_in, const int* in_sizes, int n_in,
                              void* d_out, int out_size, void* d_ws, size_t ws_size,
                              hipStream_t stream) {
    const float* x  = (const float*)d_in[0];
    const float* W  = (const float*)d_in[2];   // W_qkv [768, 2304]
    const float* bq = (const float*)d_in[3];   // b_qkv [2304]
    float* ws = (float*)d_ws;
    float* out = (float*)d_out;

    k_fold<<<dim3(BATCH, HEADS), 512, 0, stream>>>(x, W, bq, ws + WS_WTIL, ws + WS_DBIAS);
    k_dots<<<dim3(BATCH, 37), 256, 0, stream>>>(x, ws + WS_WTIL, ws + WS_DBIAS,
                                                ws + WS_DOTS);
    const int write_ft = (out_size > (int)O_FT) ? 1 : 0;
    k_catopk<<<BATCH, 512, 0, stream>>>(ws + WS_DOTS, out, (int*)(ws + WS_IND), write_ft);
    k_bcast<<<2048, 256, 0, stream>>>((const int*)(ws + WS_IND), x, out);
}